// Round 11
// baseline (599.254 us; speedup 1.0000x reference)
//
#include <hip/hip_runtime.h>
#include <hip/hip_bf16.h>
#include <type_traits>

typedef __bf16 bf16_t;
typedef __bf16 bf16x8 __attribute__((ext_vector_type(8)));
typedef float floatx4 __attribute__((ext_vector_type(4)));
typedef short v2s __attribute__((ext_vector_type(2)));

#define NN 50000
#define EE 800000
#define DD 128

// ---- ws layout (bytes) ----
#define W1T_OFF   256                                  // [128][288] (K 272->288 zero-pad)
#define W2T_OFF   (W1T_OFF + (size_t)128 * 288 * 2)    // [128][128]
#define NW1T_OFF  (W2T_OFF + (size_t)128 * 128 * 2)    // [128][256]
#define NW2T_OFF  (NW1T_OFF + (size_t)128 * 256 * 2)   // [128][128]
#define BIASF_OFF (NW2T_OFF + (size_t)128 * 128 * 2)   // float[512]: b1|b2|nb1|nb2
#define XB_OFF    207360                               // bf16 x copy [NN][DD]
#define AGG_OFF   (XB_OFF + (size_t)NN * DD * 2)       // bf16 agg [NN][DD]
#define AGG_BYTES ((size_t)NN * DD * 2)
#define WS_V2     (AGG_OFF + AGG_BYTES)                // 25,807,360 (proven available)
#define P_OFF     WS_V2                                // bf16 P = x @ eW1[0:128]
#define Q_OFF     (P_OFF + (size_t)NN * DD * 2)        // bf16 Q = x @ eW1[128:256]
#define WS_V3     (Q_OFF + (size_t)NN * DD * 2)        // 51,407,360 (proven available)
// v6 sort: packed uint2 per edge = {row | col<<16, perm}; padded cursors
#define EPK_OFF    WS_V3                               // uint2[EE]
#define RSTART_OFF (EPK_OFF + (size_t)EE * 8)          // int[NN+1]
#define RPAD_OFF   (RSTART_OFF + (size_t)(NN + 4) * 4) // int[NN*8] padded cursors
#define WS_V6      (RPAD_OFF + (size_t)NN * 32)        // 59,607,376 < 61,607,376 proven

#define NTILES (EE / 64)      // 12500 exact
#define NB_CONV 3125          // conv/hist/zero blocks (3125*2048 = 6.4M elems exact)
#define NB_PREP 403           // weight-prep blocks
#define NB_K1   (NB_CONV + NB_PREP)

// LDS pitches (bf16 elems). PB=48 is the proven config (r10: PBE=36 broke 16B
// alignment of bf16x8 LDS ops -> split accesses, -38% edge perf. Keep 48.)
#define PA 304   // v2 edge A pitch
#define PB 48    // B chunk pitch (32 + 16 pad)
#define PN 272   // node A pitch (256 + 16 pad)
#define PH 136   // h/x pitch (128 + 8 pad)

__device__ inline int load_idx(const void* ei, int i64, size_t pos)
{
    return i64 ? (int)((const long long*)ei)[pos] : ((const int*)ei)[pos];
}

// silu via v_rcp_f32: avoids the exact-div sequence; error << bf16 rounding.
__device__ inline float fast_silu(float v)
{
    float e = __expf(-v);
    return v * __builtin_amdgcn_rcpf(1.0f + e);
}

__device__ inline float ldf(const void* p, int f32, size_t i)
{
    return f32 ? ((const float*)p)[i] : (float)((const bf16_t*)p)[i];
}

template <typename FT>
__device__ inline void cp8(bf16_t* dst, const FT* src)
{
    if constexpr (std::is_same<FT, float>::value) {
#pragma unroll
        for (int i = 0; i < 8; i += 4) {
            float4 v = *(const float4*)(src + i);
            dst[i + 0] = (bf16_t)v.x; dst[i + 1] = (bf16_t)v.y;
            dst[i + 2] = (bf16_t)v.z; dst[i + 3] = (bf16_t)v.w;
        }
    } else {
        *(bf16x8*)dst = *(const bf16x8*)src;
    }
}

// 8-elem load + convert into registers (for tile prefetch)
__device__ inline bf16x8 ld8cv(const void* p, int f32, size_t off)
{
    bf16x8 r;
    if (f32) {
        const float* s = (const float*)p + off;
        float4 a = *(const float4*)s;
        float4 b = *(const float4*)(s + 4);
        r[0] = (bf16_t)a.x; r[1] = (bf16_t)a.y; r[2] = (bf16_t)a.z; r[3] = (bf16_t)a.w;
        r[4] = (bf16_t)b.x; r[5] = (bf16_t)b.y; r[6] = (bf16_t)b.z; r[7] = (bf16_t)b.w;
    } else {
        r = *(const bf16x8*)((const bf16_t*)p + off);
    }
    return r;
}

__device__ inline void pk_atomic_add_bf16(bf16_t* addr, float lo, float hi)
{
#if __has_builtin(__builtin_amdgcn_global_atomic_fadd_v2bf16)
    union { bf16_t b[2]; v2s s; } pk;
    pk.b[0] = (bf16_t)lo;
    pk.b[1] = (bf16_t)hi;
    (void)__builtin_amdgcn_global_atomic_fadd_v2bf16((v2s*)addr, pk.s);
#else
    unsigned int* w = (unsigned int*)addr;
    unsigned int old = __hip_atomic_load(w, __ATOMIC_RELAXED, __HIP_MEMORY_SCOPE_AGENT);
    while (true) {
        union { unsigned int u; bf16_t b[2]; } cur;
        cur.u = old;
        cur.b[0] = (bf16_t)((float)cur.b[0] + lo);
        cur.b[1] = (bf16_t)((float)cur.b[1] + hi);
        unsigned int prev = atomicCAS(w, old, cur.u);
        if (prev == old) break;
        old = prev;
    }
#endif
}

// ======== K1: fused detect + conv_x + agg-zero + row-hist + weight-prep ========
__global__ __launch_bounds__(256) void fused_prep_kernel(
    const void* __restrict__ x, const void* __restrict__ ei,
    const void* __restrict__ eW1, const void* __restrict__ eW2,
    const void* __restrict__ nW1, const void* __restrict__ nW2,
    const void* __restrict__ b1, const void* __restrict__ b2,
    const void* __restrict__ nb1, const void* __restrict__ nb2,
    bf16_t* __restrict__ W1t, bf16_t* __restrict__ W2t,
    bf16_t* __restrict__ nW1t, bf16_t* __restrict__ nW2t,
    float* __restrict__ biasF, bf16_t* __restrict__ xb,
    bf16_t* __restrict__ agg, int* __restrict__ rpad,
    int* __restrict__ flags, int do_sort)
{
    __shared__ int sf[2];
    const int tid = threadIdx.x;
    const int b = blockIdx.x;

    if (tid == 0) {
        const unsigned short* xraw = (const unsigned short*)x;
        const unsigned int* eiraw = (const unsigned int*)ei;
        int cnt = 0;
#pragma unroll
        for (int i = 0; i < 64; ++i) {
            unsigned short u = xraw[2 * i];
            int ex = (u >> 7) & 0xFF;
            if (ex >= 100 && ex <= 140) cnt++;
        }
        int zc = 0;
#pragma unroll
        for (int i = 0; i < 32; ++i)
            if (eiraw[2 * i + 1] == 0u) zc++;
        sf[0] = (cnt < 32) ? 1 : 0;   // 1 => fp32
        sf[1] = (zc >= 16) ? 1 : 0;   // 1 => int64
        if (b == 0) { flags[0] = sf[0]; flags[1] = sf[1]; }
    }
    __syncthreads();
    const int f32 = sf[0];
    const int i64 = sf[1];

    if (b < NB_CONV) {
        size_t i = ((size_t)b * 256 + tid) * 8;
        bf16x8 v;
        if (f32) {
            float4 a = *(const float4*)((const float*)x + i);
            float4 c = *(const float4*)((const float*)x + i + 4);
            v[0] = (bf16_t)a.x; v[1] = (bf16_t)a.y; v[2] = (bf16_t)a.z; v[3] = (bf16_t)a.w;
            v[4] = (bf16_t)c.x; v[5] = (bf16_t)c.y; v[6] = (bf16_t)c.z; v[7] = (bf16_t)c.w;
        } else {
            v = *(const bf16x8*)((const bf16_t*)x + i);
        }
        *(bf16x8*)(xb + i) = v;
        bf16x8 z;
#pragma unroll
        for (int j = 0; j < 8; ++j) z[j] = (bf16_t)0.0f;
        *(bf16x8*)(agg + i) = z;
        if (do_sort) {
            size_t e = (size_t)b * 256 + tid;   // exact: 3125*256 = 800000
            int row = min(max(load_idx(ei, i64, e), 0), NN - 1);
            atomicAdd(&rpad[row * 8], 1);
        }
    } else {
        int idx = (b - NB_CONV) * 256 + tid;
        if (idx < 128 * 288) {
            int n = idx / 288;
            int k = idx - n * 288;
            W1t[idx] = (k < 272) ? (bf16_t)ldf(eW1, f32, (size_t)k * 128 + n) : (bf16_t)0.0f;
        } else if (idx < 128 * 288 + 128 * 128) {
            int j = idx - 128 * 288;
            int n = j >> 7, k = j & 127;
            W2t[j] = (bf16_t)ldf(eW2, f32, (size_t)k * 128 + n);
        } else if (idx < 128 * 288 + 128 * 128 + 128 * 256) {
            int j = idx - (128 * 288 + 128 * 128);
            int n = j >> 8, k = j & 255;
            nW1t[j] = (bf16_t)ldf(nW1, f32, (size_t)k * 128 + n);
        } else if (idx < 102400) {
            int j = idx - (128 * 288 + 128 * 128 + 128 * 256);
            int n = j >> 7, k = j & 127;
            nW2t[j] = (bf16_t)ldf(nW2, f32, (size_t)k * 128 + n);
        } else if (idx < 102912) {
            int j = idx - 102400;
            int which = j >> 7, c = j & 127;
            const void* src = which == 0 ? b1 : which == 1 ? b2 : which == 2 ? nb1 : nb2;
            biasF[j] = ldf(src, f32, c);
        }
    }
}

// ---- sort scatter: one returning atomic (padded cursor) + one 8B store per edge ----
__global__ __launch_bounds__(256) void row_scatter_kernel(
    const void* __restrict__ ei, const int* __restrict__ rstart,
    int* __restrict__ rpad, uint2* __restrict__ epk,
    const int* __restrict__ flags)
{
    const int i64 = flags[1];
    size_t e = (size_t)blockIdx.x * 256 + threadIdx.x;
    int row = min(max(load_idx(ei, i64, e), 0), NN - 1);
    int col = min(max(load_idx(ei, i64, (size_t)EE + e), 0), NN - 1);
    int pos = rstart[row] + atomicAdd(&rpad[row * 8 + 1], 1);
    epk[pos] = make_uint2((unsigned)row | ((unsigned)col << 16), (unsigned)e);
}

// ---- pq: P = xb @ eW1[0:128], Q = xb @ eW1[128:256]; last block runs the scan ----
__global__ __launch_bounds__(256) void pq_kernel(
    const bf16_t* __restrict__ xb, const bf16_t* __restrict__ W1t,
    bf16_t* __restrict__ P, bf16_t* __restrict__ Q,
    const int* __restrict__ rpad, int* __restrict__ rstart, int do_scan)
{
    __shared__ bf16_t sX[64 * PH];
    __shared__ bf16_t sB[128 * PB];
    __shared__ int chunk[256];
    const int tid = threadIdx.x;

    if (do_scan && blockIdx.x == gridDim.x - 1) {
        // 50K exclusive scan over padded counts, overlapped with pq blocks
        const int C = (NN + 255) / 256;   // 196
        const int lo = tid * C;
        const int hi = min(lo + C, NN);
        int s = 0;
        for (int i = lo; i < hi; ++i) s += rpad[(size_t)i * 8];
        chunk[tid] = s;
        __syncthreads();
        if (tid == 0) {
            int run = 0;
            for (int i = 0; i < 256; ++i) { int v = chunk[i]; chunk[i] = run; run += v; }
        }
        __syncthreads();
        int run = chunk[tid];
        for (int i = lo; i < hi; ++i) { rstart[i] = run; run += rpad[(size_t)i * 8]; }
        if (tid == 255) rstart[NN] = run;   // == EE
        return;
    }

    const int n0 = blockIdx.x * 64;
    {
        const int m = tid >> 2;
        const int part = tid & 3;
        int n = n0 + m;
        if (n >= NN) n = NN - 1;
        const bf16x8* src = (const bf16x8*)(xb + (size_t)n * DD + part * 32);
        bf16x8* dst = (bf16x8*)&sX[m * PH + part * 32];
#pragma unroll
        for (int i = 0; i < 4; ++i) dst[i] = src[i];
    }

    const int lane = tid & 63;
    const int wv = tid >> 6;
    const int ml = lane & 15;
    const int q = lane >> 4;
    const int m0 = wv * 16;
    const floatx4 fzero = {0.f, 0.f, 0.f, 0.f};

    for (int pass = 0; pass < 2; ++pass) {
        floatx4 acc[8];
#pragma unroll
        for (int i = 0; i < 8; ++i) acc[i] = fzero;

        for (int kc = 0; kc < 4; ++kc) {
            __syncthreads();
            {
                const int n = tid >> 1;
                const int half = tid & 1;
                const bf16x8* src = (const bf16x8*)(W1t + n * 288 + pass * 128 + kc * 32 + half * 16);
                bf16x8* dst = (bf16x8*)&sB[n * PB + half * 16];
                dst[0] = src[0];
                dst[1] = src[1];
            }
            __syncthreads();
            const bf16x8 a = *(const bf16x8*)&sX[(m0 + ml) * PH + kc * 32 + q * 8];
#pragma unroll
            for (int nt = 0; nt < 8; ++nt) {
                const bf16x8 b = *(const bf16x8*)&sB[(nt * 16 + ml) * PB + q * 8];
                acc[nt] = __builtin_amdgcn_mfma_f32_16x16x32_bf16(a, b, acc[nt], 0, 0, 0);
            }
        }

        bf16_t* dst = pass ? Q : P;
#pragma unroll
        for (int r = 0; r < 4; ++r) {
            const int n = n0 + m0 + q * 4 + r;
#pragma unroll
            for (int nt = 0; nt < 8; ++nt) {
                float v = acc[nt][r];
                const float pv = __shfl_xor(v, 1, 64);
                if (((lane & 1) == 0) && n < NN) {
                    union { bf16_t b[2]; unsigned int u; } pk;
                    pk.b[0] = (bf16_t)v;
                    pk.b[1] = (bf16_t)pv;
                    *(unsigned int*)(dst + (size_t)n * DD + nt * 16 + ml) = pk.u;
                }
            }
        }
    }
}

// ======== edge v8: r8-proven v6 structure + 2-tile software pipeline ========
// Each block does tiles {2b, 2b+1}. Tile1's epk/P/Q/ea are prefetched into
// REGISTERS during tile0's compute (silu1 + W2 loop ~2000cy hides ~500-900cy
// gather latency). sH/sEA/sIdx are wave-private -> restage needs no barrier;
// only sB (cross-wave) is restaged behind one barrier.
__global__ __launch_bounds__(256) void edge_kernel_v8(
    const uint2* __restrict__ epk, const void* __restrict__ ea,
    const bf16_t* __restrict__ P, const bf16_t* __restrict__ Q,
    const bf16_t* __restrict__ W1t, const bf16_t* __restrict__ W2t,
    const float* __restrict__ biasF,
    bf16_t* __restrict__ agg, const int* __restrict__ flags)
{
    const int f32 = flags[0];

    __shared__ bf16_t sH[64 * PH];    // P+Q sum -> h -> m (all wave-private rows)
    __shared__ bf16_t sEA[64 * 32];   // ea tile, k 16..31 zero (wave-private rows)
    __shared__ bf16_t sB[128 * PB];   // B staging: W1t ea-chunk, then W2 chunks
    __shared__ int    sIdx[2][64];    // sorted dest row per edge, per tile

    const int tid = threadIdx.x;
    const int t0 = blockIdx.x * 2;    // two 64-edge tiles per block
    const int m = tid >> 2;
    const int part = tid & 3;
    const int lane = tid & 63;
    const int wv = tid >> 6;
    const int ml = lane & 15;
    const int q = lane >> 4;
    const int m0 = wv * 16;
    const floatx4 fzero = {0.f, 0.f, 0.f, 0.f};

    // ---- prologue: stage tile0 (global -> LDS) ----
    {
        const uint2 v = epk[(size_t)t0 * 64 + m];
        const int rn = (int)(v.x & 0xFFFFu);
        const int cn = (int)(v.x >> 16);
        if (part == 0) sIdx[0][m] = rn;
        const bf16x8* pr = (const bf16x8*)(P + (size_t)rn * DD + part * 32);
        const bf16x8* qc = (const bf16x8*)(Q + (size_t)cn * DD + part * 32);
#pragma unroll
        for (int i = 0; i < 4; ++i) {
            bf16x8 a = pr[i], b = qc[i], o;
#pragma unroll
            for (int j = 0; j < 8; ++j) o[j] = (bf16_t)((float)a[j] + (float)b[j]);
            *(bf16x8*)&sH[m * PH + part * 32 + i * 8] = o;
        }
        if (part < 2) {
            *(bf16x8*)&sEA[m * 32 + part * 8] = ld8cv(ea, f32, (size_t)v.y * 16 + part * 8);
        } else {
            *(float4*)&sEA[m * 32 + part * 8] = make_float4(0.f, 0.f, 0.f, 0.f);
        }
        {
            const int n = tid >> 1;
            const int half = tid & 1;
            const bf16x8* src = (const bf16x8*)(W1t + n * 288 + 256 + half * 16);
            bf16x8* dst = (bf16x8*)&sB[n * PB + half * 16];
            dst[0] = src[0];
            dst[1] = src[1];
        }
    }
    __syncthreads();

    uint2 v1;
    bf16x8 rP1[4], rQ1[4], rEA1;

#pragma unroll
    for (int tt = 0; tt < 2; ++tt) {
        // ---- ea contribution: one K=32 MFMA chunk ----
        floatx4 acc[8];
        {
            const bf16x8 a = *(const bf16x8*)&sEA[(m0 + ml) * 32 + q * 8];
#pragma unroll
            for (int nt = 0; nt < 8; ++nt) {
                const bf16x8 b = *(const bf16x8*)&sB[(nt * 16 + ml) * PB + q * 8];
                acc[nt] = __builtin_amdgcn_mfma_f32_16x16x32_bf16(a, b, fzero, 0, 0, 0);
            }
        }

        // ---- prefetch tile1 into registers (latency hides under silu1+W2 loop) ----
        if (tt == 0) {
            v1 = epk[(size_t)(t0 + 1) * 64 + m];
            const int rn1 = (int)(v1.x & 0xFFFFu);
            const int cn1 = (int)(v1.x >> 16);
#pragma unroll
            for (int i = 0; i < 4; ++i) {
                rP1[i] = *(const bf16x8*)(P + (size_t)rn1 * DD + part * 32 + i * 8);
                rQ1[i] = *(const bf16x8*)(Q + (size_t)cn1 * DD + part * 32 + i * 8);
            }
            if (part < 2)
                rEA1 = ld8cv(ea, f32, (size_t)v1.y * 16 + part * 8);
        }

        // ---- h = silu(acc + (P+Q) + b1), in place (wave-private rows) ----
#pragma unroll
        for (int nt = 0; nt < 8; ++nt) {
            const float bias = biasF[nt * 16 + ml];
#pragma unroll
            for (int r = 0; r < 4; ++r) {
                const int row = m0 + q * 4 + r;
                const int col = nt * 16 + ml;
                float v = acc[nt][r] + bias + (float)sH[row * PH + col];
                sH[row * PH + col] = (bf16_t)fast_silu(v);
            }
        }

        // ---- layer 2: [64x128] @ [128x128], 4 K-chunks ----
        floatx4 acc2[8];
#pragma unroll
        for (int i = 0; i < 8; ++i) acc2[i] = fzero;

        for (int kc = 0; kc < 4; ++kc) {
            __syncthreads();
            {
                const int n = tid >> 1;
                const int half = tid & 1;
                const bf16x8* src = (const bf16x8*)(W2t + n * 128 + kc * 32 + half * 16);
                bf16x8* dst = (bf16x8*)&sB[n * PB + half * 16];
                dst[0] = src[0];
                dst[1] = src[1];
            }
            __syncthreads();
            const bf16x8 a = *(const bf16x8*)&sH[(m0 + ml) * PH + kc * 32 + q * 8];
#pragma unroll
            for (int nt = 0; nt < 8; ++nt) {
                const bf16x8 b = *(const bf16x8*)&sB[(nt * 16 + ml) * PB + q * 8];
                acc2[nt] = __builtin_amdgcn_mfma_f32_16x16x32_bf16(a, b, acc2[nt], 0, 0, 0);
            }
        }

        // ---- m = silu(acc2 + b2) -> sH (wave-private rows; h dead now) ----
#pragma unroll
        for (int r = 0; r < 4; ++r) {
#pragma unroll
            for (int nt = 0; nt < 8; ++nt) {
                float v = fast_silu(acc2[nt][r] + biasF[128 + nt * 16 + ml]);
                const float pv = __shfl_xor(v, 1, 64);
                if ((ml & 1) == 0) {
                    union { bf16_t b[2]; unsigned int u; } pk;
                    pk.b[0] = (bf16_t)v;
                    pk.b[1] = (bf16_t)pv;
                    *(unsigned int*)&sH[(m0 + q * 4 + r) * PH + nt * 16 + ml] = pk.u;
                }
            }
        }

        // ---- wave-local segment reduce over sorted rows; one atomic per segment ----
        {
            float lo = 0.f, hi = 0.f;
            int curRow = sIdx[tt][m0];
#pragma unroll
            for (int i = 0; i < 16; ++i) {
                const int r = sIdx[tt][m0 + i];
                if (r != curRow) {
                    pk_atomic_add_bf16(agg + (size_t)curRow * DD + lane * 2, lo, hi);
                    lo = 0.f; hi = 0.f;
                    curRow = r;
                }
                union { unsigned int u; bf16_t b[2]; } pk;
                pk.u = *(const unsigned int*)&sH[(m0 + i) * PH + lane * 2];
                lo += (float)pk.b[0];
                hi += (float)pk.b[1];
            }
            pk_atomic_add_bf16(agg + (size_t)curRow * DD + lane * 2, lo, hi);
        }

        // ---- interlude: stage tile1 from registers ----
        if (tt == 0) {
            __syncthreads();   // all waves past last sB (W2) reads
            if (part == 0) sIdx[1][m] = (int)(v1.x & 0xFFFFu);
#pragma unroll
            for (int i = 0; i < 4; ++i) {
                bf16x8 a = rP1[i], b = rQ1[i], o;
#pragma unroll
                for (int j = 0; j < 8; ++j) o[j] = (bf16_t)((float)a[j] + (float)b[j]);
                *(bf16x8*)&sH[m * PH + part * 32 + i * 8] = o;
            }
            if (part < 2) {
                *(bf16x8*)&sEA[m * 32 + part * 8] = rEA1;
            } else {
                *(float4*)&sEA[m * 32 + part * 8] = make_float4(0.f, 0.f, 0.f, 0.f);
            }
            {
                const int n = tid >> 1;
                const int half = tid & 1;
                const bf16x8* src = (const bf16x8*)(W1t + n * 288 + 256 + half * 16);
                bf16x8* dst = (bf16x8*)&sB[n * PB + half * 16];
                dst[0] = src[0];
                dst[1] = src[1];
            }
            __syncthreads();
        }
    }
}

// ======== edge v3 (fallback: ws fits P/Q but not sort arrays) ========
__global__ __launch_bounds__(256) void edge_kernel_v3(
    const void* __restrict__ ei, const void* __restrict__ ea,
    const bf16_t* __restrict__ P, const bf16_t* __restrict__ Q,
    const bf16_t* __restrict__ W1t, const bf16_t* __restrict__ W2t,
    const float* __restrict__ biasF,
    bf16_t* __restrict__ agg, const int* __restrict__ flags)
{
    const int f32 = flags[0];
    const int i64 = flags[1];

    __shared__ bf16_t sH[64 * PH];
    __shared__ bf16_t sEA[64 * 32];
    __shared__ bf16_t sB[128 * PB];
    const int tid = threadIdx.x;
    const int e0 = blockIdx.x * 64;

    {
        const int m = tid >> 2;
        const int part = tid & 3;
        const int e = e0 + m;
        int rn = load_idx(ei, i64, e);
        int cn = load_idx(ei, i64, (size_t)EE + e);
        rn = min(max(rn, 0), NN - 1);
        cn = min(max(cn, 0), NN - 1);
        const bf16x8* pr = (const bf16x8*)(P + (size_t)rn * DD + part * 32);
        const bf16x8* qc = (const bf16x8*)(Q + (size_t)cn * DD + part * 32);
#pragma unroll
        for (int i = 0; i < 4; ++i) {
            bf16x8 a = pr[i], b = qc[i], o;
#pragma unroll
            for (int j = 0; j < 8; ++j) o[j] = (bf16_t)((float)a[j] + (float)b[j]);
            *(bf16x8*)&sH[m * PH + part * 32 + i * 8] = o;
        }
        if (part < 2) {
            if (f32) cp8<float>(&sEA[m * 32 + part * 8], (const float*)ea + (size_t)e * 16 + part * 8);
            else     cp8<bf16_t>(&sEA[m * 32 + part * 8], (const bf16_t*)ea + (size_t)e * 16 + part * 8);
        } else {
            *(float4*)&sEA[m * 32 + part * 8] = make_float4(0.f, 0.f, 0.f, 0.f);
        }
        {
            const int n = tid >> 1;
            const int half = tid & 1;
            const bf16x8* src = (const bf16x8*)(W1t + n * 288 + 256 + half * 16);
            bf16x8* dst = (bf16x8*)&sB[n * PB + half * 16];
            dst[0] = src[0];
            dst[1] = src[1];
        }
    }
    __syncthreads();

    const int lane = tid & 63;
    const int wv = tid >> 6;
    const int ml = lane & 15;
    const int q = lane >> 4;
    const int m0 = wv * 16;
    const floatx4 fzero = {0.f, 0.f, 0.f, 0.f};

    floatx4 acc[8];
#pragma unroll
    for (int i = 0; i < 8; ++i) acc[i] = fzero;
    {
        const bf16x8 a = *(const bf16x8*)&sEA[(m0 + ml) * 32 + q * 8];
#pragma unroll
        for (int nt = 0; nt < 8; ++nt) {
            const bf16x8 b = *(const bf16x8*)&sB[(nt * 16 + ml) * PB + q * 8];
            acc[nt] = __builtin_amdgcn_mfma_f32_16x16x32_bf16(a, b, acc[nt], 0, 0, 0);
        }
    }

#pragma unroll
    for (int nt = 0; nt < 8; ++nt) {
        const float bias = biasF[nt * 16 + ml];
#pragma unroll
        for (int r = 0; r < 4; ++r) {
            const int row = m0 + q * 4 + r;
            const int col = nt * 16 + ml;
            float v = acc[nt][r] + bias + (float)sH[row * PH + col];
            sH[row * PH + col] = (bf16_t)fast_silu(v);
        }
    }

    floatx4 acc2[8];
#pragma unroll
    for (int i = 0; i < 8; ++i) acc2[i] = fzero;

    for (int kc = 0; kc < 4; ++kc) {
        __syncthreads();
        {
            const int n = tid >> 1;
            const int half = tid & 1;
            const bf16x8* src = (const bf16x8*)(W2t + n * 128 + kc * 32 + half * 16);
            bf16x8* dst = (bf16x8*)&sB[n * PB + half * 16];
            dst[0] = src[0];
            dst[1] = src[1];
        }
        __syncthreads();
        const bf16x8 a = *(const bf16x8*)&sH[(m0 + ml) * PH + kc * 32 + q * 8];
#pragma unroll
        for (int nt = 0; nt < 8; ++nt) {
            const bf16x8 b = *(const bf16x8*)&sB[(nt * 16 + ml) * PB + q * 8];
            acc2[nt] = __builtin_amdgcn_mfma_f32_16x16x32_bf16(a, b, acc2[nt], 0, 0, 0);
        }
    }

#pragma unroll
    for (int r = 0; r < 4; ++r) {
        const int e = e0 + m0 + q * 4 + r;
        int rn = load_idx(ei, i64, e);
        rn = min(max(rn, 0), NN - 1);
#pragma unroll
        for (int nt = 0; nt < 8; ++nt) {
            float v = fast_silu(acc2[nt][r] + biasF[128 + nt * 16 + ml]);
            const float pv = __shfl_xor(v, 1, 64);
            if ((ml & 1) == 0)
                pk_atomic_add_bf16(agg + (size_t)rn * DD + nt * 16 + ml, v, pv);
        }
    }
}

// ======== edge v2 (fallback if ws too small for P/Q) ========
__global__ __launch_bounds__(256) void edge_kernel_v2(
    const bf16_t* __restrict__ xb, const void* __restrict__ ei,
    const void* __restrict__ ea,
    const bf16_t* __restrict__ W1t, const bf16_t* __restrict__ W2t,
    const float* __restrict__ biasF,
    bf16_t* __restrict__ agg, const int* __restrict__ flags)
{
    const int f32 = flags[0];
    const int i64 = flags[1];

    __shared__ bf16_t sA[64 * PA];
    __shared__ bf16_t sB[128 * PB];
    const int tid = threadIdx.x;
    const int e0 = blockIdx.x * 64;

    {
        const int m = tid >> 2;
        const int part = tid & 3;
        const int e = e0 + m;
        int rn = load_idx(ei, i64, e);
        int cn = load_idx(ei, i64, (size_t)EE + e);
        rn = min(max(rn, 0), NN - 1);
        cn = min(max(cn, 0), NN - 1);
        const bf16x8* xr = (const bf16x8*)(xb + (size_t)rn * DD + part * 32);
        const bf16x8* xc = (const bf16x8*)(xb + (size_t)cn * DD + part * 32);
        bf16x8* dR = (bf16x8*)&sA[m * PA + part * 32];
        bf16x8* dC = (bf16x8*)&sA[m * PA + 128 + part * 32];
#pragma unroll
        for (int i = 0; i < 4; ++i) dR[i] = xr[i];
#pragma unroll
        for (int i = 0; i < 4; ++i) dC[i] = xc[i];
        if (part < 2) {
            if (f32) cp8<float>(&sA[m * PA + 256 + part * 8], (const float*)ea + (size_t)e * 16 + part * 8);
            else     cp8<bf16_t>(&sA[m * PA + 256 + part * 8], (const bf16_t*)ea + (size_t)e * 16 + part * 8);
        } else {
            *(float4*)&sA[m * PA + 256 + part * 8] = make_float4(0.f, 0.f, 0.f, 0.f);
        }
    }

    const int lane = tid & 63;
    const int wv = tid >> 6;
    const int ml = lane & 15;
    const int q = lane >> 4;
    const int m0 = wv * 16;

    const floatx4 fzero = {0.f, 0.f, 0.f, 0.f};
    floatx4 acc[8];
#pragma unroll
    for (int i = 0; i < 8; ++i) acc[i] = fzero;

    for (int kc = 0; kc < 9; ++kc) {
        __syncthreads();
        {
            const int n = tid >> 1;
            const int half = tid & 1;
            const bf16x8* src = (const bf16x8*)(W1t + n * 288 + kc * 32 + half * 16);
            bf16x8* dst = (bf16x8*)&sB[n * PB + half * 16];
            dst[0] = src[0];
            dst[1] = src[1];
        }
        __syncthreads();
        const bf16x8 a = *(const bf16x8*)&sA[(m0 + ml) * PA + kc * 32 + q * 8];
#pragma unroll
        for (int nt = 0; nt < 8; ++nt) {
            const bf16x8 b = *(const bf16x8*)&sB[(nt * 16 + ml) * PB + q * 8];
            acc[nt] = __builtin_amdgcn_mfma_f32_16x16x32_bf16(a, b, acc[nt], 0, 0, 0);
        }
    }

#pragma unroll
    for (int nt = 0; nt < 8; ++nt) {
        const float bias = biasF[nt * 16 + ml];
#pragma unroll
        for (int r = 0; r < 4; ++r) {
            float v = acc[nt][r] + bias;
            sA[(m0 + q * 4 + r) * PA + nt * 16 + ml] = (bf16_t)fast_silu(v);
        }
    }
    __syncthreads();

    floatx4 acc2[8];
#pragma unroll
    for (int i = 0; i < 8; ++i) acc2[i] = fzero;

    for (int kc = 0; kc < 4; ++kc) {
        __syncthreads();
        {
            const int n = tid >> 1;
            const int half = tid & 1;
            const bf16x8* src = (const bf16x8*)(W2t + n * 128 + kc * 32 + half * 16);
            bf16x8* dst = (bf16x8*)&sB[n * PB + half * 16];
            dst[0] = src[0];
            dst[1] = src[1];
        }
        __syncthreads();
        const bf16x8 a = *(const bf16x8*)&sA[(m0 + ml) * PA + kc * 32 + q * 8];
#pragma unroll
        for (int nt = 0; nt < 8; ++nt) {
            const bf16x8 b = *(const bf16x8*)&sB[(nt * 16 + ml) * PB + q * 8];
            acc2[nt] = __builtin_amdgcn_mfma_f32_16x16x32_bf16(a, b, acc2[nt], 0, 0, 0);
        }
    }

    float bias2[8];
#pragma unroll
    for (int nt = 0; nt < 8; ++nt) bias2[nt] = biasF[128 + nt * 16 + ml];
#pragma unroll
    for (int r = 0; r < 4; ++r) {
        const int e = e0 + m0 + q * 4 + r;
        int rn = load_idx(ei, i64, e);
        rn = min(max(rn, 0), NN - 1);
#pragma unroll
        for (int nt = 0; nt < 8; ++nt) {
            float v = fast_silu(acc2[nt][r] + bias2[nt]);
            const float pv = __shfl_xor(v, 1, 64);
            if ((ml & 1) == 0)
                pk_atomic_add_bf16(agg + (size_t)rn * DD + nt * 16 + ml, v, pv);
        }
    }
}

// -------- node MLP (runtime dtype): out = x + (silu([xb|agg]@nW1+nb1)@nW2+nb2) ----
__global__ __launch_bounds__(256) void node_kernel_v3(
    const void* __restrict__ x, const bf16_t* __restrict__ xb,
    const bf16_t* __restrict__ agg,
    const bf16_t* __restrict__ nW1t, const bf16_t* __restrict__ nW2t,
    const float* __restrict__ biasF,
    void* __restrict__ out, const int* __restrict__ flags)
{
    const int f32 = flags[0];

    __shared__ bf16_t sA[64 * PN];
    __shared__ bf16_t sB[128 * PB];
    const int tid = threadIdx.x;
    const int n0 = blockIdx.x * 64;

    {
        const int m = tid >> 2;
        const int p = tid & 3;
        int n = n0 + m;
        if (n >= NN) n = NN - 1;
        const bf16_t* srcbase = (p < 2) ? xb : agg;
        const int col = (p & 1) * 64;
        const bf16x8* src = (const bf16x8*)(srcbase + (size_t)n * DD + col);
        bf16x8* dst = (bf16x8*)&sA[m * PN + (p >> 1) * 128 + col];
#pragma unroll
        for (int i = 0; i < 8; ++i) dst[i] = src[i];
    }

    const int lane = tid & 63;
    const int wv = tid >> 6;
    const int ml = lane & 15;
    const int q = lane >> 4;
    const int m0 = wv * 16;

    const floatx4 fzero = {0.f, 0.f, 0.f, 0.f};
    floatx4 acc[8];
#pragma unroll
    for (int i = 0; i < 8; ++i) acc[i] = fzero;

    for (int kc = 0; kc < 8; ++kc) {
        __syncthreads();
        {
            const int n = tid >> 1;
            const int half = tid & 1;
            const bf16x8* src = (const bf16x8*)(nW1t + n * 256 + kc * 32 + half * 16);
            bf16x8* dst = (bf16x8*)&sB[n * PB + half * 16];
            dst[0] = src[0];
            dst[1] = src[1];
        }
        __syncthreads();
        const bf16x8 a = *(const bf16x8*)&sA[(m0 + ml) * PN + kc * 32 + q * 8];
#pragma unroll
        for (int nt = 0; nt < 8; ++nt) {
            const bf16x8 b = *(const bf16x8*)&sB[(nt * 16 + ml) * PB + q * 8];
            acc[nt] = __builtin_amdgcn_mfma_f32_16x16x32_bf16(a, b, acc[nt], 0, 0, 0);
        }
    }

#pragma unroll
    for (int nt = 0; nt < 8; ++nt) {
        const float bias = biasF[256 + nt * 16 + ml];
#pragma unroll
        for (int r = 0; r < 4; ++r) {
            float v = acc[nt][r] + bias;
            sA[(m0 + q * 4 + r) * PN + nt * 16 + ml] = (bf16_t)fast_silu(v);
        }
    }
    __syncthreads();

    floatx4 acc2[8];
#pragma unroll
    for (int i = 0; i < 8; ++i) acc2[i] = fzero;

    for (int kc = 0; kc < 4; ++kc) {
        __syncthreads();
        {
            const int n = tid >> 1;
            const int half = tid & 1;
            const bf16x8* src = (const bf16x8*)(nW2t + n * 128 + kc * 32 + half * 16);
            bf16x8* dst = (bf16x8*)&sB[n * PB + half * 16];
            dst[0] = src[0];
            dst[1] = src[1];
        }
        __syncthreads();
        const bf16x8 a = *(const bf16x8*)&sA[(m0 + ml) * PN + kc * 32 + q * 8];
#pragma unroll
        for (int nt = 0; nt < 8; ++nt) {
            const bf16x8 b = *(const bf16x8*)&sB[(nt * 16 + ml) * PB + q * 8];
            acc2[nt] = __builtin_amdgcn_mfma_f32_16x16x32_bf16(a, b, acc2[nt], 0, 0, 0);
        }
    }

#pragma unroll
    for (int r = 0; r < 4; ++r) {
        const int n = n0 + m0 + q * 4 + r;
        if (n < NN) {
#pragma unroll
            for (int nt = 0; nt < 8; ++nt) {
                const int col = nt * 16 + ml;
                const size_t off = (size_t)n * DD + col;
                float v = acc2[nt][r] + biasF[384 + col];
                if (f32) {
                    float xv = ((const float*)x)[off];
                    ((float*)out)[off] = xv + v;
                } else {
                    float xv = (float)((const bf16_t*)x)[off];
                    ((bf16_t*)out)[off] = (bf16_t)(xv + v);
                }
            }
        }
    }
}

extern "C" void kernel_launch(void* const* d_in, const int* in_sizes, int n_in,
                              void* d_out, int out_size, void* d_ws, size_t ws_size,
                              hipStream_t stream)
{
    const void* x   = d_in[0];
    const void* ei  = d_in[1];
    const void* ea  = d_in[2];
    const void* eW1 = d_in[3];
    const void* eb1 = d_in[4];
    const void* eW2 = d_in[5];
    const void* eb2 = d_in[6];
    const void* nW1 = d_in[7];
    const void* nb1 = d_in[8];
    const void* nW2 = d_in[9];
    const void* nb2 = d_in[10];

    char* ws = (char*)d_ws;
    int*    flags  = (int*)ws;
    bf16_t* W1t    = (bf16_t*)(ws + W1T_OFF);
    bf16_t* W2t    = (bf16_t*)(ws + W2T_OFF);
    bf16_t* nW1t   = (bf16_t*)(ws + NW1T_OFF);
    bf16_t* nW2t   = (bf16_t*)(ws + NW2T_OFF);
    float*  biasF  = (float*)(ws + BIASF_OFF);
    bf16_t* xb     = (bf16_t*)(ws + XB_OFF);
    bf16_t* agg    = (bf16_t*)(ws + AGG_OFF);
    bf16_t* P      = (bf16_t*)(ws + P_OFF);
    bf16_t* Q      = (bf16_t*)(ws + Q_OFF);
    uint2*  epk    = (uint2*)(ws + EPK_OFF);
    int*    rstart = (int*)(ws + RSTART_OFF);
    int*    rpad   = (int*)(ws + RPAD_OFF);

    const int do_sort = (ws_size >= WS_V6) ? 1 : 0;

    if (do_sort)
        (void)hipMemsetAsync(rpad, 0, (size_t)NN * 32, stream);

    fused_prep_kernel<<<NB_K1, 256, 0, stream>>>(
        x, ei, eW1, eW2, nW1, nW2, eb1, eb2, nb1, nb2,
        W1t, W2t, nW1t, nW2t, biasF, xb, agg, rpad, flags, do_sort);

    if (do_sort) {
        pq_kernel<<<(NN + 63) / 64 + 1, 256, 0, stream>>>(xb, W1t, P, Q, rpad, rstart, 1);
        row_scatter_kernel<<<EE / 256, 256, 0, stream>>>(ei, rstart, rpad, epk, flags);
        edge_kernel_v8<<<NTILES / 2, 256, 0, stream>>>(epk, ea, P, Q, W1t, W2t, biasF, agg, flags);
    } else if (ws_size >= WS_V3) {
        pq_kernel<<<(NN + 63) / 64, 256, 0, stream>>>(xb, W1t, P, Q, rpad, rstart, 0);
        edge_kernel_v3<<<EE / 64, 256, 0, stream>>>(ei, ea, P, Q, W1t, W2t, biasF, agg, flags);
    } else {
        edge_kernel_v2<<<EE / 64, 256, 0, stream>>>(xb, ei, ea, W1t, W2t, biasF, agg, flags);
    }

    node_kernel_v3<<<(NN + 63) / 64, 256, 0, stream>>>(
        x, xb, agg, nW1t, nW2t, biasF, d_out, flags);
}

// Round 12
// 500.900 us; speedup vs baseline: 1.1964x; 1.1964x over previous
//
#include <hip/hip_runtime.h>
#include <hip/hip_bf16.h>
#include <type_traits>

typedef __bf16 bf16_t;
typedef __bf16 bf16x8 __attribute__((ext_vector_type(8)));
typedef float floatx4 __attribute__((ext_vector_type(4)));
typedef short v2s __attribute__((ext_vector_type(2)));

#define NN 50000
#define EE 800000
#define DD 128

// ---- ws layout (bytes) ----
#define W1T_OFF   256                                  // [128][288] (K 272->288 zero-pad)
#define W2T_OFF   (W1T_OFF + (size_t)128 * 288 * 2)    // [128][128]
#define NW1T_OFF  (W2T_OFF + (size_t)128 * 128 * 2)    // [128][256]
#define NW2T_OFF  (NW1T_OFF + (size_t)128 * 256 * 2)   // [128][128]
#define BIASF_OFF (NW2T_OFF + (size_t)128 * 128 * 2)   // float[512]: b1|b2|nb1|nb2
#define XB_OFF    207360                               // bf16 x copy [NN][DD]
#define AGG_OFF   (XB_OFF + (size_t)NN * DD * 2)       // bf16 agg [NN][DD]
#define AGG_BYTES ((size_t)NN * DD * 2)
#define WS_V2     (AGG_OFF + AGG_BYTES)                // 25,807,360 (proven available)
#define P_OFF     WS_V2                                // bf16 P = x @ eW1[0:128]
#define Q_OFF     (P_OFF + (size_t)NN * DD * 2)        // bf16 Q = x @ eW1[128:256]
#define WS_V3     (Q_OFF + (size_t)NN * DD * 2)        // 51,407,360 (proven available)
// v6 sort: packed uint2 per edge = {row | col<<16, perm}; padded cursors
#define EPK_OFF    WS_V3                               // uint2[EE]
#define RSTART_OFF (EPK_OFF + (size_t)EE * 8)          // int[NN+1]
#define RPAD_OFF   (RSTART_OFF + (size_t)(NN + 4) * 4) // int[NN*8] padded cursors
#define WS_V6      (RPAD_OFF + (size_t)NN * 32)        // 59,607,376 < 61,607,376 proven

#define NTILES (EE / 64)      // 12500 exact
#define NB_CONV 3125          // conv/hist/zero blocks (3125*2048 = 6.4M elems exact)
#define NB_PREP 403           // weight-prep blocks
#define NB_K1   (NB_CONV + NB_PREP)
#define NB_PQ   ((NN + 63) / 64)   // 782 pq blocks
#define NB_SCAT (EE / 256)         // 3125 scatter blocks

// LDS pitches (bf16 elems). PB=48 is the proven config (r10: PBE=36 broke 16B
// alignment of bf16x8 LDS ops -> split accesses. r9/r11 edge micro-opts also
// regressed — edge v6 @ r8 config is the proven local optimum; do not touch.)
#define PA 304   // v2 edge A pitch
#define PB 48    // B chunk pitch (32 + 16 pad)
#define PN 272   // node A pitch (256 + 16 pad)
#define PH 136   // h/x pitch (128 + 8 pad)

__device__ inline int load_idx(const void* ei, int i64, size_t pos)
{
    return i64 ? (int)((const long long*)ei)[pos] : ((const int*)ei)[pos];
}

// silu via v_rcp_f32: avoids the exact-div sequence; error << bf16 rounding.
__device__ inline float fast_silu(float v)
{
    float e = __expf(-v);
    return v * __builtin_amdgcn_rcpf(1.0f + e);
}

__device__ inline float ldf(const void* p, int f32, size_t i)
{
    return f32 ? ((const float*)p)[i] : (float)((const bf16_t*)p)[i];
}

template <typename FT>
__device__ inline void cp8(bf16_t* dst, const FT* src)
{
    if constexpr (std::is_same<FT, float>::value) {
#pragma unroll
        for (int i = 0; i < 8; i += 4) {
            float4 v = *(const float4*)(src + i);
            dst[i + 0] = (bf16_t)v.x; dst[i + 1] = (bf16_t)v.y;
            dst[i + 2] = (bf16_t)v.z; dst[i + 3] = (bf16_t)v.w;
        }
    } else {
        *(bf16x8*)dst = *(const bf16x8*)src;
    }
}

__device__ inline void pk_atomic_add_bf16(bf16_t* addr, float lo, float hi)
{
#if __has_builtin(__builtin_amdgcn_global_atomic_fadd_v2bf16)
    union { bf16_t b[2]; v2s s; } pk;
    pk.b[0] = (bf16_t)lo;
    pk.b[1] = (bf16_t)hi;
    (void)__builtin_amdgcn_global_atomic_fadd_v2bf16((v2s*)addr, pk.s);
#else
    unsigned int* w = (unsigned int*)addr;
    unsigned int old = __hip_atomic_load(w, __ATOMIC_RELAXED, __HIP_MEMORY_SCOPE_AGENT);
    while (true) {
        union { unsigned int u; bf16_t b[2]; } cur;
        cur.u = old;
        cur.b[0] = (bf16_t)((float)cur.b[0] + lo);
        cur.b[1] = (bf16_t)((float)cur.b[1] + hi);
        unsigned int prev = atomicCAS(w, old, cur.u);
        if (prev == old) break;
        old = prev;
    }
#endif
}

// ======== K1: fused detect + conv_x + agg-zero + row-hist + weight-prep ========
__global__ __launch_bounds__(256) void fused_prep_kernel(
    const void* __restrict__ x, const void* __restrict__ ei,
    const void* __restrict__ eW1, const void* __restrict__ eW2,
    const void* __restrict__ nW1, const void* __restrict__ nW2,
    const void* __restrict__ b1, const void* __restrict__ b2,
    const void* __restrict__ nb1, const void* __restrict__ nb2,
    bf16_t* __restrict__ W1t, bf16_t* __restrict__ W2t,
    bf16_t* __restrict__ nW1t, bf16_t* __restrict__ nW2t,
    float* __restrict__ biasF, bf16_t* __restrict__ xb,
    bf16_t* __restrict__ agg, int* __restrict__ rpad,
    int* __restrict__ flags, int do_sort)
{
    __shared__ int sf[2];
    const int tid = threadIdx.x;
    const int b = blockIdx.x;

    if (tid == 0) {
        const unsigned short* xraw = (const unsigned short*)x;
        const unsigned int* eiraw = (const unsigned int*)ei;
        int cnt = 0;
#pragma unroll
        for (int i = 0; i < 64; ++i) {
            unsigned short u = xraw[2 * i];
            int ex = (u >> 7) & 0xFF;
            if (ex >= 100 && ex <= 140) cnt++;
        }
        int zc = 0;
#pragma unroll
        for (int i = 0; i < 32; ++i)
            if (eiraw[2 * i + 1] == 0u) zc++;
        sf[0] = (cnt < 32) ? 1 : 0;   // 1 => fp32
        sf[1] = (zc >= 16) ? 1 : 0;   // 1 => int64
        if (b == 0) { flags[0] = sf[0]; flags[1] = sf[1]; }
    }
    __syncthreads();
    const int f32 = sf[0];
    const int i64 = sf[1];

    if (b < NB_CONV) {
        size_t i = ((size_t)b * 256 + tid) * 8;
        bf16x8 v;
        if (f32) {
            float4 a = *(const float4*)((const float*)x + i);
            float4 c = *(const float4*)((const float*)x + i + 4);
            v[0] = (bf16_t)a.x; v[1] = (bf16_t)a.y; v[2] = (bf16_t)a.z; v[3] = (bf16_t)a.w;
            v[4] = (bf16_t)c.x; v[5] = (bf16_t)c.y; v[6] = (bf16_t)c.z; v[7] = (bf16_t)c.w;
        } else {
            v = *(const bf16x8*)((const bf16_t*)x + i);
        }
        *(bf16x8*)(xb + i) = v;
        bf16x8 z;
#pragma unroll
        for (int j = 0; j < 8; ++j) z[j] = (bf16_t)0.0f;
        *(bf16x8*)(agg + i) = z;
        if (do_sort) {
            size_t e = (size_t)b * 256 + tid;   // exact: 3125*256 = 800000
            int row = min(max(load_idx(ei, i64, e), 0), NN - 1);
            atomicAdd(&rpad[row * 8], 1);
        }
    } else {
        int idx = (b - NB_CONV) * 256 + tid;
        if (idx < 128 * 288) {
            int n = idx / 288;
            int k = idx - n * 288;
            W1t[idx] = (k < 272) ? (bf16_t)ldf(eW1, f32, (size_t)k * 128 + n) : (bf16_t)0.0f;
        } else if (idx < 128 * 288 + 128 * 128) {
            int j = idx - 128 * 288;
            int n = j >> 7, k = j & 127;
            W2t[j] = (bf16_t)ldf(eW2, f32, (size_t)k * 128 + n);
        } else if (idx < 128 * 288 + 128 * 128 + 128 * 256) {
            int j = idx - (128 * 288 + 128 * 128);
            int n = j >> 8, k = j & 255;
            nW1t[j] = (bf16_t)ldf(nW1, f32, (size_t)k * 128 + n);
        } else if (idx < 102400) {
            int j = idx - (128 * 288 + 128 * 128 + 128 * 256);
            int n = j >> 7, k = j & 127;
            nW2t[j] = (bf16_t)ldf(nW2, f32, (size_t)k * 128 + n);
        } else if (idx < 102912) {
            int j = idx - 102400;
            int which = j >> 7, c = j & 127;
            const void* src = which == 0 ? b1 : which == 1 ? b2 : which == 2 ? nb1 : nb2;
            biasF[j] = ldf(src, f32, c);
        }
    }
}

// ---- standalone 50K exclusive scan over padded counts (1 block, ~10us) ----
__global__ __launch_bounds__(256) void row_scan_kernel(
    const int* __restrict__ rpad, int* __restrict__ rstart)
{
    __shared__ int chunk[256];
    const int tid = threadIdx.x;
    const int C = (NN + 255) / 256;   // 196
    const int lo = tid * C;
    const int hi = min(lo + C, NN);
    int s = 0;
    for (int i = lo; i < hi; ++i) s += rpad[(size_t)i * 8];
    chunk[tid] = s;
    __syncthreads();
    if (tid == 0) {
        int run = 0;
        for (int i = 0; i < 256; ++i) { int v = chunk[i]; chunk[i] = run; run += v; }
    }
    __syncthreads();
    int run = chunk[tid];
    for (int i = lo; i < hi; ++i) { rstart[i] = run; run += rpad[(size_t)i * 8]; }
    if (tid == 255) rstart[NN] = run;   // == EE
}

// ---- merged pq + scatter: blocks [0,n_pq) do pq; [n_pq, n_pq+NB_SCAT) scatter.
// The two are independent (scatter: hist+scan done; pq: xb+W1t done) -> overlap
// scatter's atomic-latency waves with pq's MFMA waves.
__global__ __launch_bounds__(256) void pq_scatter_kernel(
    const bf16_t* __restrict__ xb, const bf16_t* __restrict__ W1t,
    bf16_t* __restrict__ P, bf16_t* __restrict__ Q,
    const void* __restrict__ ei, const int* __restrict__ rstart,
    int* __restrict__ rpad, uint2* __restrict__ epk,
    const int* __restrict__ flags, int n_pq)
{
    const int tid = threadIdx.x;

    if ((int)blockIdx.x >= n_pq) {
        // ---- scatter: one returning atomic (padded cursor) + one 8B store ----
        const int i64 = flags[1];
        size_t e = (size_t)(blockIdx.x - n_pq) * 256 + tid;
        int row = min(max(load_idx(ei, i64, e), 0), NN - 1);
        int col = min(max(load_idx(ei, i64, (size_t)EE + e), 0), NN - 1);
        int pos = rstart[row] + atomicAdd(&rpad[row * 8 + 1], 1);
        epk[pos] = make_uint2((unsigned)row | ((unsigned)col << 16), (unsigned)e);
        return;
    }

    __shared__ bf16_t sX[64 * PH];
    __shared__ bf16_t sB[128 * PB];

    const int n0 = blockIdx.x * 64;
    {
        const int m = tid >> 2;
        const int part = tid & 3;
        int n = n0 + m;
        if (n >= NN) n = NN - 1;
        const bf16x8* src = (const bf16x8*)(xb + (size_t)n * DD + part * 32);
        bf16x8* dst = (bf16x8*)&sX[m * PH + part * 32];
#pragma unroll
        for (int i = 0; i < 4; ++i) dst[i] = src[i];
    }

    const int lane = tid & 63;
    const int wv = tid >> 6;
    const int ml = lane & 15;
    const int q = lane >> 4;
    const int m0 = wv * 16;
    const floatx4 fzero = {0.f, 0.f, 0.f, 0.f};

    for (int pass = 0; pass < 2; ++pass) {
        floatx4 acc[8];
#pragma unroll
        for (int i = 0; i < 8; ++i) acc[i] = fzero;

        for (int kc = 0; kc < 4; ++kc) {
            __syncthreads();
            {
                const int n = tid >> 1;
                const int half = tid & 1;
                const bf16x8* src = (const bf16x8*)(W1t + n * 288 + pass * 128 + kc * 32 + half * 16);
                bf16x8* dst = (bf16x8*)&sB[n * PB + half * 16];
                dst[0] = src[0];
                dst[1] = src[1];
            }
            __syncthreads();
            const bf16x8 a = *(const bf16x8*)&sX[(m0 + ml) * PH + kc * 32 + q * 8];
#pragma unroll
            for (int nt = 0; nt < 8; ++nt) {
                const bf16x8 b = *(const bf16x8*)&sB[(nt * 16 + ml) * PB + q * 8];
                acc[nt] = __builtin_amdgcn_mfma_f32_16x16x32_bf16(a, b, acc[nt], 0, 0, 0);
            }
        }

        bf16_t* dst = pass ? Q : P;
#pragma unroll
        for (int r = 0; r < 4; ++r) {
            const int n = n0 + m0 + q * 4 + r;
#pragma unroll
            for (int nt = 0; nt < 8; ++nt) {
                float v = acc[nt][r];
                const float pv = __shfl_xor(v, 1, 64);
                if (((lane & 1) == 0) && n < NN) {
                    union { bf16_t b[2]; unsigned int u; } pk;
                    pk.b[0] = (bf16_t)v;
                    pk.b[1] = (bf16_t)pv;
                    *(unsigned int*)(dst + (size_t)n * DD + nt * 16 + ml) = pk.u;
                }
            }
        }
    }
}

// ======== edge v6: row-sorted edges + in-tile segment merge (r8 exact, proven) ====
__global__ __launch_bounds__(256) void edge_kernel_v6(
    const uint2* __restrict__ epk, const void* __restrict__ ea,
    const bf16_t* __restrict__ P, const bf16_t* __restrict__ Q,
    const bf16_t* __restrict__ W1t, const bf16_t* __restrict__ W2t,
    const float* __restrict__ biasF,
    bf16_t* __restrict__ agg, const int* __restrict__ flags)
{
    const int f32 = flags[0];

    __shared__ bf16_t sH[64 * PH];    // P+Q sum -> h -> m (all wave-private rows)
    __shared__ bf16_t sEA[64 * 32];   // ea tile, k 16..31 zero
    __shared__ bf16_t sB[128 * PB];   // B staging: W1t ea-chunk, then W2 chunks
    __shared__ int    sIdx[64];       // sorted dest row per edge

    const int tid = threadIdx.x;
    const int t = blockIdx.x;         // one 64-edge tile per block

    {
        const int m = tid >> 2;
        const int part = tid & 3;
        const uint2 v = epk[(size_t)t * 64 + m];
        const int rn = (int)(v.x & 0xFFFFu);
        const int cn = (int)(v.x >> 16);
        if (part == 0) sIdx[m] = rn;
        const bf16x8* pr = (const bf16x8*)(P + (size_t)rn * DD + part * 32);
        const bf16x8* qc = (const bf16x8*)(Q + (size_t)cn * DD + part * 32);
#pragma unroll
        for (int i = 0; i < 4; ++i) {
            bf16x8 a = pr[i], b = qc[i], o;
#pragma unroll
            for (int j = 0; j < 8; ++j) o[j] = (bf16_t)((float)a[j] + (float)b[j]);
            *(bf16x8*)&sH[m * PH + part * 32 + i * 8] = o;
        }
        if (part < 2) {
            const int ep = (int)v.y;
            if (f32) cp8<float>(&sEA[m * 32 + part * 8], (const float*)ea + (size_t)ep * 16 + part * 8);
            else     cp8<bf16_t>(&sEA[m * 32 + part * 8], (const bf16_t*)ea + (size_t)ep * 16 + part * 8);
        } else {
            *(float4*)&sEA[m * 32 + part * 8] = make_float4(0.f, 0.f, 0.f, 0.f);
        }
        {
            const int n = tid >> 1;
            const int half = tid & 1;
            const bf16x8* src = (const bf16x8*)(W1t + n * 288 + 256 + half * 16);
            bf16x8* dst = (bf16x8*)&sB[n * PB + half * 16];
            dst[0] = src[0];
            dst[1] = src[1];
        }
    }
    __syncthreads();

    const int lane = tid & 63;
    const int wv = tid >> 6;
    const int ml = lane & 15;
    const int q = lane >> 4;
    const int m0 = wv * 16;
    const floatx4 fzero = {0.f, 0.f, 0.f, 0.f};

    floatx4 acc[8];
    {
        const bf16x8 a = *(const bf16x8*)&sEA[(m0 + ml) * 32 + q * 8];
#pragma unroll
        for (int nt = 0; nt < 8; ++nt) {
            const bf16x8 b = *(const bf16x8*)&sB[(nt * 16 + ml) * PB + q * 8];
            acc[nt] = __builtin_amdgcn_mfma_f32_16x16x32_bf16(a, b, fzero, 0, 0, 0);
        }
    }

#pragma unroll
    for (int nt = 0; nt < 8; ++nt) {
        const float bias = biasF[nt * 16 + ml];
#pragma unroll
        for (int r = 0; r < 4; ++r) {
            const int row = m0 + q * 4 + r;
            const int col = nt * 16 + ml;
            float v = acc[nt][r] + bias + (float)sH[row * PH + col];
            sH[row * PH + col] = (bf16_t)fast_silu(v);
        }
    }

    floatx4 acc2[8];
#pragma unroll
    for (int i = 0; i < 8; ++i) acc2[i] = fzero;

    for (int kc = 0; kc < 4; ++kc) {
        __syncthreads();
        {
            const int n = tid >> 1;
            const int half = tid & 1;
            const bf16x8* src = (const bf16x8*)(W2t + n * 128 + kc * 32 + half * 16);
            bf16x8* dst = (bf16x8*)&sB[n * PB + half * 16];
            dst[0] = src[0];
            dst[1] = src[1];
        }
        __syncthreads();
        const bf16x8 a = *(const bf16x8*)&sH[(m0 + ml) * PH + kc * 32 + q * 8];
#pragma unroll
        for (int nt = 0; nt < 8; ++nt) {
            const bf16x8 b = *(const bf16x8*)&sB[(nt * 16 + ml) * PB + q * 8];
            acc2[nt] = __builtin_amdgcn_mfma_f32_16x16x32_bf16(a, b, acc2[nt], 0, 0, 0);
        }
    }

#pragma unroll
    for (int r = 0; r < 4; ++r) {
#pragma unroll
        for (int nt = 0; nt < 8; ++nt) {
            float v = fast_silu(acc2[nt][r] + biasF[128 + nt * 16 + ml]);
            const float pv = __shfl_xor(v, 1, 64);
            if ((ml & 1) == 0) {
                union { bf16_t b[2]; unsigned int u; } pk;
                pk.b[0] = (bf16_t)v;
                pk.b[1] = (bf16_t)pv;
                *(unsigned int*)&sH[(m0 + q * 4 + r) * PH + nt * 16 + ml] = pk.u;
            }
        }
    }

    {
        float lo = 0.f, hi = 0.f;
        int curRow = sIdx[m0];
#pragma unroll
        for (int i = 0; i < 16; ++i) {
            const int r = sIdx[m0 + i];
            if (r != curRow) {
                pk_atomic_add_bf16(agg + (size_t)curRow * DD + lane * 2, lo, hi);
                lo = 0.f; hi = 0.f;
                curRow = r;
            }
            union { unsigned int u; bf16_t b[2]; } pk;
            pk.u = *(const unsigned int*)&sH[(m0 + i) * PH + lane * 2];
            lo += (float)pk.b[0];
            hi += (float)pk.b[1];
        }
        pk_atomic_add_bf16(agg + (size_t)curRow * DD + lane * 2, lo, hi);
    }
}

// ======== edge v3 (fallback: ws fits P/Q but not sort arrays) ========
__global__ __launch_bounds__(256) void edge_kernel_v3(
    const void* __restrict__ ei, const void* __restrict__ ea,
    const bf16_t* __restrict__ P, const bf16_t* __restrict__ Q,
    const bf16_t* __restrict__ W1t, const bf16_t* __restrict__ W2t,
    const float* __restrict__ biasF,
    bf16_t* __restrict__ agg, const int* __restrict__ flags)
{
    const int f32 = flags[0];
    const int i64 = flags[1];

    __shared__ bf16_t sH[64 * PH];
    __shared__ bf16_t sEA[64 * 32];
    __shared__ bf16_t sB[128 * PB];
    const int tid = threadIdx.x;
    const int e0 = blockIdx.x * 64;

    {
        const int m = tid >> 2;
        const int part = tid & 3;
        const int e = e0 + m;
        int rn = load_idx(ei, i64, e);
        int cn = load_idx(ei, i64, (size_t)EE + e);
        rn = min(max(rn, 0), NN - 1);
        cn = min(max(cn, 0), NN - 1);
        const bf16x8* pr = (const bf16x8*)(P + (size_t)rn * DD + part * 32);
        const bf16x8* qc = (const bf16x8*)(Q + (size_t)cn * DD + part * 32);
#pragma unroll
        for (int i = 0; i < 4; ++i) {
            bf16x8 a = pr[i], b = qc[i], o;
#pragma unroll
            for (int j = 0; j < 8; ++j) o[j] = (bf16_t)((float)a[j] + (float)b[j]);
            *(bf16x8*)&sH[m * PH + part * 32 + i * 8] = o;
        }
        if (part < 2) {
            if (f32) cp8<float>(&sEA[m * 32 + part * 8], (const float*)ea + (size_t)e * 16 + part * 8);
            else     cp8<bf16_t>(&sEA[m * 32 + part * 8], (const bf16_t*)ea + (size_t)e * 16 + part * 8);
        } else {
            *(float4*)&sEA[m * 32 + part * 8] = make_float4(0.f, 0.f, 0.f, 0.f);
        }
        {
            const int n = tid >> 1;
            const int half = tid & 1;
            const bf16x8* src = (const bf16x8*)(W1t + n * 288 + 256 + half * 16);
            bf16x8* dst = (bf16x8*)&sB[n * PB + half * 16];
            dst[0] = src[0];
            dst[1] = src[1];
        }
    }
    __syncthreads();

    const int lane = tid & 63;
    const int wv = tid >> 6;
    const int ml = lane & 15;
    const int q = lane >> 4;
    const int m0 = wv * 16;
    const floatx4 fzero = {0.f, 0.f, 0.f, 0.f};

    floatx4 acc[8];
#pragma unroll
    for (int i = 0; i < 8; ++i) acc[i] = fzero;
    {
        const bf16x8 a = *(const bf16x8*)&sEA[(m0 + ml) * 32 + q * 8];
#pragma unroll
        for (int nt = 0; nt < 8; ++nt) {
            const bf16x8 b = *(const bf16x8*)&sB[(nt * 16 + ml) * PB + q * 8];
            acc[nt] = __builtin_amdgcn_mfma_f32_16x16x32_bf16(a, b, acc[nt], 0, 0, 0);
        }
    }

#pragma unroll
    for (int nt = 0; nt < 8; ++nt) {
        const float bias = biasF[nt * 16 + ml];
#pragma unroll
        for (int r = 0; r < 4; ++r) {
            const int row = m0 + q * 4 + r;
            const int col = nt * 16 + ml;
            float v = acc[nt][r] + bias + (float)sH[row * PH + col];
            sH[row * PH + col] = (bf16_t)fast_silu(v);
        }
    }

    floatx4 acc2[8];
#pragma unroll
    for (int i = 0; i < 8; ++i) acc2[i] = fzero;

    for (int kc = 0; kc < 4; ++kc) {
        __syncthreads();
        {
            const int n = tid >> 1;
            const int half = tid & 1;
            const bf16x8* src = (const bf16x8*)(W2t + n * 128 + kc * 32 + half * 16);
            bf16x8* dst = (bf16x8*)&sB[n * PB + half * 16];
            dst[0] = src[0];
            dst[1] = src[1];
        }
        __syncthreads();
        const bf16x8 a = *(const bf16x8*)&sH[(m0 + ml) * PH + kc * 32 + q * 8];
#pragma unroll
        for (int nt = 0; nt < 8; ++nt) {
            const bf16x8 b = *(const bf16x8*)&sB[(nt * 16 + ml) * PB + q * 8];
            acc2[nt] = __builtin_amdgcn_mfma_f32_16x16x32_bf16(a, b, acc2[nt], 0, 0, 0);
        }
    }

#pragma unroll
    for (int r = 0; r < 4; ++r) {
        const int e = e0 + m0 + q * 4 + r;
        int rn = load_idx(ei, i64, e);
        rn = min(max(rn, 0), NN - 1);
#pragma unroll
        for (int nt = 0; nt < 8; ++nt) {
            float v = fast_silu(acc2[nt][r] + biasF[128 + nt * 16 + ml]);
            const float pv = __shfl_xor(v, 1, 64);
            if ((ml & 1) == 0)
                pk_atomic_add_bf16(agg + (size_t)rn * DD + nt * 16 + ml, v, pv);
        }
    }
}

// ======== edge v2 (fallback if ws too small for P/Q) ========
__global__ __launch_bounds__(256) void edge_kernel_v2(
    const bf16_t* __restrict__ xb, const void* __restrict__ ei,
    const void* __restrict__ ea,
    const bf16_t* __restrict__ W1t, const bf16_t* __restrict__ W2t,
    const float* __restrict__ biasF,
    bf16_t* __restrict__ agg, const int* __restrict__ flags)
{
    const int f32 = flags[0];
    const int i64 = flags[1];

    __shared__ bf16_t sA[64 * PA];
    __shared__ bf16_t sB[128 * PB];
    const int tid = threadIdx.x;
    const int e0 = blockIdx.x * 64;

    {
        const int m = tid >> 2;
        const int part = tid & 3;
        const int e = e0 + m;
        int rn = load_idx(ei, i64, e);
        int cn = load_idx(ei, i64, (size_t)EE + e);
        rn = min(max(rn, 0), NN - 1);
        cn = min(max(cn, 0), NN - 1);
        const bf16x8* xr = (const bf16x8*)(xb + (size_t)rn * DD + part * 32);
        const bf16x8* xc = (const bf16x8*)(xb + (size_t)cn * DD + part * 32);
        bf16x8* dR = (bf16x8*)&sA[m * PA + part * 32];
        bf16x8* dC = (bf16x8*)&sA[m * PA + 128 + part * 32];
#pragma unroll
        for (int i = 0; i < 4; ++i) dR[i] = xr[i];
#pragma unroll
        for (int i = 0; i < 4; ++i) dC[i] = xc[i];
        if (part < 2) {
            if (f32) cp8<float>(&sA[m * PA + 256 + part * 8], (const float*)ea + (size_t)e * 16 + part * 8);
            else     cp8<bf16_t>(&sA[m * PA + 256 + part * 8], (const bf16_t*)ea + (size_t)e * 16 + part * 8);
        } else {
            *(float4*)&sA[m * PA + 256 + part * 8] = make_float4(0.f, 0.f, 0.f, 0.f);
        }
    }

    const int lane = tid & 63;
    const int wv = tid >> 6;
    const int ml = lane & 15;
    const int q = lane >> 4;
    const int m0 = wv * 16;

    const floatx4 fzero = {0.f, 0.f, 0.f, 0.f};
    floatx4 acc[8];
#pragma unroll
    for (int i = 0; i < 8; ++i) acc[i] = fzero;

    for (int kc = 0; kc < 9; ++kc) {
        __syncthreads();
        {
            const int n = tid >> 1;
            const int half = tid & 1;
            const bf16x8* src = (const bf16x8*)(W1t + n * 288 + kc * 32 + half * 16);
            bf16x8* dst = (bf16x8*)&sB[n * PB + half * 16];
            dst[0] = src[0];
            dst[1] = src[1];
        }
        __syncthreads();
        const bf16x8 a = *(const bf16x8*)&sA[(m0 + ml) * PA + kc * 32 + q * 8];
#pragma unroll
        for (int nt = 0; nt < 8; ++nt) {
            const bf16x8 b = *(const bf16x8*)&sB[(nt * 16 + ml) * PB + q * 8];
            acc[nt] = __builtin_amdgcn_mfma_f32_16x16x32_bf16(a, b, acc[nt], 0, 0, 0);
        }
    }

#pragma unroll
    for (int nt = 0; nt < 8; ++nt) {
        const float bias = biasF[nt * 16 + ml];
#pragma unroll
        for (int r = 0; r < 4; ++r) {
            float v = acc[nt][r] + bias;
            sA[(m0 + q * 4 + r) * PA + nt * 16 + ml] = (bf16_t)fast_silu(v);
        }
    }
    __syncthreads();

    floatx4 acc2[8];
#pragma unroll
    for (int i = 0; i < 8; ++i) acc2[i] = fzero;

    for (int kc = 0; kc < 4; ++kc) {
        __syncthreads();
        {
            const int n = tid >> 1;
            const int half = tid & 1;
            const bf16x8* src = (const bf16x8*)(W2t + n * 128 + kc * 32 + half * 16);
            bf16x8* dst = (bf16x8*)&sB[n * PB + half * 16];
            dst[0] = src[0];
            dst[1] = src[1];
        }
        __syncthreads();
        const bf16x8 a = *(const bf16x8*)&sA[(m0 + ml) * PA + kc * 32 + q * 8];
#pragma unroll
        for (int nt = 0; nt < 8; ++nt) {
            const bf16x8 b = *(const bf16x8*)&sB[(nt * 16 + ml) * PB + q * 8];
            acc2[nt] = __builtin_amdgcn_mfma_f32_16x16x32_bf16(a, b, acc2[nt], 0, 0, 0);
        }
    }

    float bias2[8];
#pragma unroll
    for (int nt = 0; nt < 8; ++nt) bias2[nt] = biasF[128 + nt * 16 + ml];
#pragma unroll
    for (int r = 0; r < 4; ++r) {
        const int e = e0 + m0 + q * 4 + r;
        int rn = load_idx(ei, i64, e);
        rn = min(max(rn, 0), NN - 1);
#pragma unroll
        for (int nt = 0; nt < 8; ++nt) {
            float v = fast_silu(acc2[nt][r] + bias2[nt]);
            const float pv = __shfl_xor(v, 1, 64);
            if ((ml & 1) == 0)
                pk_atomic_add_bf16(agg + (size_t)rn * DD + nt * 16 + ml, v, pv);
        }
    }
}

// -------- node MLP (runtime dtype): out = x + (silu([xb|agg]@nW1+nb1)@nW2+nb2) ----
__global__ __launch_bounds__(256) void node_kernel_v3(
    const void* __restrict__ x, const bf16_t* __restrict__ xb,
    const bf16_t* __restrict__ agg,
    const bf16_t* __restrict__ nW1t, const bf16_t* __restrict__ nW2t,
    const float* __restrict__ biasF,
    void* __restrict__ out, const int* __restrict__ flags)
{
    const int f32 = flags[0];

    __shared__ bf16_t sA[64 * PN];
    __shared__ bf16_t sB[128 * PB];
    const int tid = threadIdx.x;
    const int n0 = blockIdx.x * 64;

    {
        const int m = tid >> 2;
        const int p = tid & 3;
        int n = n0 + m;
        if (n >= NN) n = NN - 1;
        const bf16_t* srcbase = (p < 2) ? xb : agg;
        const int col = (p & 1) * 64;
        const bf16x8* src = (const bf16x8*)(srcbase + (size_t)n * DD + col);
        bf16x8* dst = (bf16x8*)&sA[m * PN + (p >> 1) * 128 + col];
#pragma unroll
        for (int i = 0; i < 8; ++i) dst[i] = src[i];
    }

    const int lane = tid & 63;
    const int wv = tid >> 6;
    const int ml = lane & 15;
    const int q = lane >> 4;
    const int m0 = wv * 16;

    const floatx4 fzero = {0.f, 0.f, 0.f, 0.f};
    floatx4 acc[8];
#pragma unroll
    for (int i = 0; i < 8; ++i) acc[i] = fzero;

    for (int kc = 0; kc < 8; ++kc) {
        __syncthreads();
        {
            const int n = tid >> 1;
            const int half = tid & 1;
            const bf16x8* src = (const bf16x8*)(nW1t + n * 256 + kc * 32 + half * 16);
            bf16x8* dst = (bf16x8*)&sB[n * PB + half * 16];
            dst[0] = src[0];
            dst[1] = src[1];
        }
        __syncthreads();
        const bf16x8 a = *(const bf16x8*)&sA[(m0 + ml) * PN + kc * 32 + q * 8];
#pragma unroll
        for (int nt = 0; nt < 8; ++nt) {
            const bf16x8 b = *(const bf16x8*)&sB[(nt * 16 + ml) * PB + q * 8];
            acc[nt] = __builtin_amdgcn_mfma_f32_16x16x32_bf16(a, b, acc[nt], 0, 0, 0);
        }
    }

#pragma unroll
    for (int nt = 0; nt < 8; ++nt) {
        const float bias = biasF[256 + nt * 16 + ml];
#pragma unroll
        for (int r = 0; r < 4; ++r) {
            float v = acc[nt][r] + bias;
            sA[(m0 + q * 4 + r) * PN + nt * 16 + ml] = (bf16_t)fast_silu(v);
        }
    }
    __syncthreads();

    floatx4 acc2[8];
#pragma unroll
    for (int i = 0; i < 8; ++i) acc2[i] = fzero;

    for (int kc = 0; kc < 4; ++kc) {
        __syncthreads();
        {
            const int n = tid >> 1;
            const int half = tid & 1;
            const bf16x8* src = (const bf16x8*)(nW2t + n * 128 + kc * 32 + half * 16);
            bf16x8* dst = (bf16x8*)&sB[n * PB + half * 16];
            dst[0] = src[0];
            dst[1] = src[1];
        }
        __syncthreads();
        const bf16x8 a = *(const bf16x8*)&sA[(m0 + ml) * PN + kc * 32 + q * 8];
#pragma unroll
        for (int nt = 0; nt < 8; ++nt) {
            const bf16x8 b = *(const bf16x8*)&sB[(nt * 16 + ml) * PB + q * 8];
            acc2[nt] = __builtin_amdgcn_mfma_f32_16x16x32_bf16(a, b, acc2[nt], 0, 0, 0);
        }
    }

#pragma unroll
    for (int r = 0; r < 4; ++r) {
        const int n = n0 + m0 + q * 4 + r;
        if (n < NN) {
#pragma unroll
            for (int nt = 0; nt < 8; ++nt) {
                const int col = nt * 16 + ml;
                const size_t off = (size_t)n * DD + col;
                float v = acc2[nt][r] + biasF[384 + col];
                if (f32) {
                    float xv = ((const float*)x)[off];
                    ((float*)out)[off] = xv + v;
                } else {
                    float xv = (float)((const bf16_t*)x)[off];
                    ((bf16_t*)out)[off] = (bf16_t)(xv + v);
                }
            }
        }
    }
}

extern "C" void kernel_launch(void* const* d_in, const int* in_sizes, int n_in,
                              void* d_out, int out_size, void* d_ws, size_t ws_size,
                              hipStream_t stream)
{
    const void* x   = d_in[0];
    const void* ei  = d_in[1];
    const void* ea  = d_in[2];
    const void* eW1 = d_in[3];
    const void* eb1 = d_in[4];
    const void* eW2 = d_in[5];
    const void* eb2 = d_in[6];
    const void* nW1 = d_in[7];
    const void* nb1 = d_in[8];
    const void* nW2 = d_in[9];
    const void* nb2 = d_in[10];

    char* ws = (char*)d_ws;
    int*    flags  = (int*)ws;
    bf16_t* W1t    = (bf16_t*)(ws + W1T_OFF);
    bf16_t* W2t    = (bf16_t*)(ws + W2T_OFF);
    bf16_t* nW1t   = (bf16_t*)(ws + NW1T_OFF);
    bf16_t* nW2t   = (bf16_t*)(ws + NW2T_OFF);
    float*  biasF  = (float*)(ws + BIASF_OFF);
    bf16_t* xb     = (bf16_t*)(ws + XB_OFF);
    bf16_t* agg    = (bf16_t*)(ws + AGG_OFF);
    bf16_t* P      = (bf16_t*)(ws + P_OFF);
    bf16_t* Q      = (bf16_t*)(ws + Q_OFF);
    uint2*  epk    = (uint2*)(ws + EPK_OFF);
    int*    rstart = (int*)(ws + RSTART_OFF);
    int*    rpad   = (int*)(ws + RPAD_OFF);

    const int do_sort = (ws_size >= WS_V6) ? 1 : 0;

    if (do_sort)
        (void)hipMemsetAsync(rpad, 0, (size_t)NN * 32, stream);

    fused_prep_kernel<<<NB_K1, 256, 0, stream>>>(
        x, ei, eW1, eW2, nW1, nW2, eb1, eb2, nb1, nb2,
        W1t, W2t, nW1t, nW2t, biasF, xb, agg, rpad, flags, do_sort);

    if (do_sort) {
        row_scan_kernel<<<1, 256, 0, stream>>>(rpad, rstart);
        pq_scatter_kernel<<<NB_PQ + NB_SCAT, 256, 0, stream>>>(
            xb, W1t, P, Q, ei, rstart, rpad, epk, flags, NB_PQ);
        edge_kernel_v6<<<NTILES, 256, 0, stream>>>(epk, ea, P, Q, W1t, W2t, biasF, agg, flags);
    } else if (ws_size >= WS_V3) {
        pq_scatter_kernel<<<NB_PQ, 256, 0, stream>>>(
            xb, W1t, P, Q, ei, rstart, rpad, epk, flags, NB_PQ);
        edge_kernel_v3<<<EE / 64, 256, 0, stream>>>(ei, ea, P, Q, W1t, W2t, biasF, agg, flags);
    } else {
        edge_kernel_v2<<<EE / 64, 256, 0, stream>>>(xb, ei, ea, W1t, W2t, biasF, agg, flags);
    }

    node_kernel_v3<<<(NN + 63) / 64, 256, 0, stream>>>(
        x, xb, agg, nW1t, nW2t, biasF, d_out, flags);
}